// Round 4
// baseline (967.569 us; speedup 1.0000x reference)
//
#include <hip/hip_runtime.h>
#include <math.h>

#define SEG 1024
#define MAXCH 2176   // chunk table entries (zero-padded); ncTotal <= 2048 by D>=65 clamp

// ---------------------------------------------------------------------------
// Phase 1: natural cubic spline coefficients, 3 channels. Single block.
// Also initializes the per-segment min-z table.
// ---------------------------------------------------------------------------
__global__ void spline_setup(const float* __restrict__ delay_in,
                             const float* __restrict__ raw,
                             double* __restrict__ coef,
                             int* __restrict__ segmin,
                             int nseg, int nf) {
    extern __shared__ double smem[];
    double* xch = smem;           // 3*nf
    double* cp  = xch + 3 * nf;   // nf
    double* kk  = cp + nf;        // 3*nf

    int tid = threadIdx.x;
    for (int i = tid; i < nseg; i += blockDim.x) segmin[i] = 0x7fffffff;

    for (int i = tid; i < nf; i += blockDim.x) {
        double s0 = 1.0 / (1.0 + exp(-(double)raw[2 * i + 0]));
        double s1 = 1.0 / (1.0 + exp(-(double)raw[2 * i + 1]));
        double ss = s0 + s1;
        xch[0 * nf + i] = (double)delay_in[i];
        xch[1 * nf + i] = s0 / ss;
        xch[2 * nf + i] = s1 / ss;
    }
    __syncthreads();

    if (tid == 0) {
        cp[0] = 0.5;
        for (int i = 1; i < nf; ++i) {
            double d = (i == nf - 1) ? 2.0 : 4.0;
            cp[i] = 1.0 / (d - cp[i - 1]);
        }
    }
    __syncthreads();

    if (tid < 3) {
        const double* x = xch + tid * nf;
        double* k = kk + tid * nf;
        double hinv = (double)(nf - 1);
        double prev = 0.0;
        for (int j = 0; j < nf; ++j) {
            double r = 0.0;
            if (j < nf - 1) r += 3.0 * hinv * (x[j + 1] - x[j]);
            if (j > 0)      r += 3.0 * hinv * (x[j] - x[j - 1]);
            double dp = (r - prev) * cp[j];
            k[j] = dp;
            prev = dp;
        }
        for (int j = nf - 2; j >= 0; --j) k[j] = k[j] - cp[j] * k[j + 1];
    }
    __syncthreads();

    int nint = nf - 1;
    double hinv = (double)(nf - 1);
    for (int w = tid; w < 3 * nint; w += blockDim.x) {
        int ch = w / nint;
        int i = w - ch * nint;
        const double* x = xch + ch * nf;
        const double* k = kk + ch * nf;
        double dx3 = 3.0 * (x[i + 1] - x[i]);
        double two_c   = (2.0 * dx3 * hinv - 4.0 * k[i] - 2.0 * k[i + 1]) * hinv;
        double three_d = (-2.0 * dx3 * hinv + 3.0 * (k[i] + k[i + 1])) * hinv * hinv;
        double* C = coef + (size_t)(ch * nint + i) * 4;
        C[0] = x[i];
        C[1] = k[i];
        C[2] = 0.5 * two_c;
        C[3] = three_d * (1.0 / 3.0);
    }
}

// ---------------------------------------------------------------------------
// Phase 2: per-sample spline eval -> {g1,g2,g3, packed(r1,r2,r3)} one float4.
// r_i = (t - z - i) & 1023 : the 3 wrapped history-read slots.
// Per-segment (1024-sample) min z via one atomic per wave.
// Pads [n, nTot) with zeros so the scan can load unguarded.
// ---------------------------------------------------------------------------
__global__ void eval_kernel(const double* __restrict__ coef,
                            float4* __restrict__ gx,
                            int* __restrict__ segmin,
                            int n, int nTot, int nf) {
    int j = blockIdx.x * blockDim.x + threadIdx.x;
    if (j >= nTot) return;
    if (j >= n) { gx[j] = make_float4(0.f, 0.f, 0.f, 0.f); return; }

    double u = (double)j / (double)(n - 1);
    double nfm1 = (double)(nf - 1);
    int idx = (int)(u * nfm1);
    if (idx > nf - 2) idx = nf - 2;
    if (idx < 0) idx = 0;
    double tknot = (double)idx / nfm1;
    if (u < tknot && idx > 0) {
        idx--; tknot = (double)idx / nfm1;
    } else {
        double tnext = (double)(idx + 1) / nfm1;
        if (u >= tnext && idx < nf - 2) { idx++; tknot = tnext; }
    }
    double f = u - tknot;

    int nint = nf - 1;
    const double* C0 = coef + (size_t)(0 * nint + idx) * 4;
    const double* C1 = coef + (size_t)(1 * nint + idx) * 4;
    const double* C2 = coef + (size_t)(2 * nint + idx) * 4;
    double dly = C0[0] + f * (C0[1] + f * (C0[2] + f * C0[3]));
    double b1d = C1[0] + f * (C1[1] + f * (C1[2] + f * C1[3]));
    double b2d = C2[0] + f * (C2[1] + f * (C2[2] + f * C2[3]));

    double zf = floor(dly);
    int z = (int)zf;
    float alfa = (float)(dly - zf);
    float b1 = (float)b1d, b2 = (float)b2d;
    float g1 = b1 * (1.0f - alfa);
    float g2 = b1 * alfa + b2 * (1.0f - alfa);
    float g3 = b2 * alfa;

    int r1 = (j - z - 1) & 1023;
    int r2 = (j - z - 2) & 1023;
    int r3 = (j - z - 3) & 1023;
    unsigned int pk = (unsigned int)((r1 << 20) | (r2 << 10) | r3);
    gx[j] = make_float4(g1, g2, g3, __uint_as_float(pk));

    int wmin = z;
    #pragma unroll
    for (int o = 32; o > 0; o >>= 1) wmin = min(wmin, __shfl_down(wmin, o, 64));
    if ((threadIdx.x & 63) == 0) atomicMin(&segmin[j >> 10], wmin);
}

// ---------------------------------------------------------------------------
// Phase 3: wave-synchronous variable-chunk recurrence. ONE wave, no barriers
// in the main loop. Chunks never cross 1024-sample segment boundaries;
// chunk length <= min(z in segment)+1 (<=256, 4 rows of 64). All history
// reads of a chunk target positions < base => reads (issued first) never
// alias the chunk's writes in the mod-1024 buffer (z+3 <= 768).
// Stream {g1,g2,g3,pk} prefetched 3 chunks deep via unroll-by-3 (no movs).
// Excitation staged in LDS (t < burst only).
// ---------------------------------------------------------------------------
__global__ void __launch_bounds__(64) scan_kernel(const float4* __restrict__ gx,
                                                  const int* __restrict__ segmin,
                                                  const float* __restrict__ exc,
                                                  float* __restrict__ y,
                                                  int n, int burst) {
    __shared__ float buf[1024];
    __shared__ float excl[2048];
    __shared__ unsigned int chunkTab[MAXCH];

    int tid = threadIdx.x;

    for (int i = tid; i < 1024; i += 64) buf[i] = 0.0f;
    for (int i = tid; i < 2048; i += 64) excl[i] = (i < burst) ? exc[i] : 0.0f;
    for (int i = tid; i < MAXCH; i += 64) chunkTab[i] = 0u;

    // ---- build chunk table (one wave, prefix scan over segments) ----
    int nseg = (n + SEG - 1) >> 10;
    int s0 = 2 * tid, s1 = 2 * tid + 1;
    int L0 = 0, D0 = 1, nc0 = 0, L1 = 0, D1 = 1, nc1 = 0;
    if (s0 < nseg) {
        L0 = n - (s0 << 10); if (L0 > SEG) L0 = SEG;
        int m = segmin[s0]; if (m > 255) m = 255; if (m < 64) m = 64;  // m<64 never observed (min z ~100)
        D0 = m + 1; nc0 = (L0 + D0 - 1) / D0;
    }
    if (s1 < nseg) {
        L1 = n - (s1 << 10); if (L1 > SEG) L1 = SEG;
        int m = segmin[s1]; if (m > 255) m = 255; if (m < 64) m = 64;
        D1 = m + 1; nc1 = (L1 + D1 - 1) / D1;
    }
    int tot = nc0 + nc1;
    int pre = tot;
    #pragma unroll
    for (int d = 1; d < 64; d <<= 1) {
        int o = __shfl_up(pre, d, 64);
        if (tid >= d) pre += o;
    }
    int ncTotal = __shfl(pre, 63, 64);
    int excl0 = pre - tot;
    if (nc0) {
        int sz = (L0 + nc0 - 1) / nc0;
        for (int c = 0; c < nc0; ++c) {
            int bb = (s0 << 10) + c * sz;
            int ll = L0 - c * sz; if (ll > sz) ll = sz; if (ll < 0) ll = 0;
            chunkTab[excl0 + c] = (unsigned int)((bb << 9) | ll);
        }
    }
    if (nc1) {
        int sz = (L1 + nc1 - 1) / nc1;
        int b1o = excl0 + nc0;
        for (int c = 0; c < nc1; ++c) {
            int bb = (s1 << 10) + c * sz;
            int ll = L1 - c * sz; if (ll > sz) ll = sz; if (ll < 0) ll = 0;
            chunkTab[b1o + c] = (unsigned int)((bb << 9) | ll);
        }
    }
    // single wave: LDS pipe is in-order, no barrier needed.

    // ---- main loop ----
    auto loadset = [&](float4& p0, float4& p1, float4& p2, float4& p3, int e) {
        int b = e >> 9, l = e & 511;
        if (l > 0)   p0 = gx[b + tid];
        if (l > 64)  p1 = gx[b + 64 + tid];
        if (l > 128) p2 = gx[b + 128 + tid];
        if (l > 192) p3 = gx[b + 192 + tid];
    };

    #define ROW(r, p, WITHX)                                                   \
    if ((r) * 64 < len) {                                                      \
        int t = b + (r) * 64 + tid;                                            \
        unsigned int pk = __float_as_uint((p).w);                              \
        float y1 = buf[pk >> 20];                                              \
        float y2 = buf[(pk >> 10) & 1023];                                     \
        float y3 = buf[pk & 1023];                                             \
        float acc;                                                             \
        if (WITHX) {                                                           \
            float xr = excl[t & 2047];                                         \
            float xv = (t < burst) ? xr : 0.0f;                                \
            acc = fmaf((p).x, y1, xv);                                         \
        } else {                                                               \
            acc = (p).x * y1;                                                  \
        }                                                                      \
        acc = fmaf((p).y, y2, acc);                                            \
        acc = fmaf((p).z, y3, acc);                                            \
        if ((r) * 64 + tid < len) {                                            \
            buf[t & 1023] = acc;                                               \
            y[t] = acc;                                                        \
        }                                                                      \
    }

    auto body = [&](float4& p0, float4& p1, float4& p2, float4& p3,
                    int& ent, int itNext) {
        int b = ent >> 9;
        int len = ent & 511;
        if (len > 0) {
            if (b < burst) {
                ROW(0, p0, 1) ROW(1, p1, 1) ROW(2, p2, 1) ROW(3, p3, 1)
            } else {
                ROW(0, p0, 0) ROW(1, p1, 0) ROW(2, p2, 0) ROW(3, p3, 0)
            }
        }
        int e2 = (int)chunkTab[itNext];
        e2 = __builtin_amdgcn_readfirstlane(e2);
        ent = e2;
        loadset(p0, p1, p2, p3, e2);
    };

    int entA = __builtin_amdgcn_readfirstlane((int)chunkTab[0]);
    int entB = __builtin_amdgcn_readfirstlane((int)chunkTab[1]);
    int entC = __builtin_amdgcn_readfirstlane((int)chunkTab[2]);
    float4 pA0, pA1, pA2, pA3, pB0, pB1, pB2, pB3, pC0, pC1, pC2, pC3;
    pA0 = pA1 = pA2 = pA3 = make_float4(0.f, 0.f, 0.f, 0.f);
    pB0 = pB1 = pB2 = pB3 = make_float4(0.f, 0.f, 0.f, 0.f);
    pC0 = pC1 = pC2 = pC3 = make_float4(0.f, 0.f, 0.f, 0.f);
    loadset(pA0, pA1, pA2, pA3, entA);
    loadset(pB0, pB1, pB2, pB3, entB);
    loadset(pC0, pC1, pC2, pC3, entC);

    int nGroups = (ncTotal + 2) / 3;
    for (int g = 0; g < nGroups; ++g) {
        int it = 3 * g;
        body(pA0, pA1, pA2, pA3, entA, it + 3);
        body(pB0, pB1, pB2, pB3, entB, it + 4);
        body(pC0, pC1, pC2, pC3, entC, it + 5);
    }
    #undef ROW
}

// ---------------------------------------------------------------------------
extern "C" void kernel_launch(void* const* d_in, const int* in_sizes, int n_in,
                              void* d_out, int out_size, void* d_ws, size_t ws_size,
                              hipStream_t stream) {
    const float* delay = (const float*)d_in[0];
    const float* raw   = (const float*)d_in[1];
    const float* exc   = (const float*)d_in[2];
    int nf = in_sizes[0];
    int burst = in_sizes[2];
    if (burst > 2048) burst = 2048;
    int n = out_size;
    int nseg = (n + SEG - 1) >> 10;
    int nTot = n + 1024;

    char* ws = (char*)d_ws;
    size_t coefBytes = (size_t)3 * (nf - 1) * 4 * sizeof(double);
    size_t off = (coefBytes + 255) & ~(size_t)255;
    double* coef = (double*)ws;
    int* segmin = (int*)(ws + off);
    off += 1024;
    float4* gxa = (float4*)(ws + off);

    size_t shmem = (size_t)(7 * nf) * sizeof(double);
    spline_setup<<<1, 64, shmem, stream>>>(delay, raw, coef, segmin, nseg, nf);
    eval_kernel<<<(nTot + 255) / 256, 256, 0, stream>>>(coef, gxa, segmin, n, nTot, nf);
    scan_kernel<<<1, 64, 0, stream>>>(gxa, segmin, exc, (float*)d_out, n, burst);
}

// Round 5
// 403.992 us; speedup vs baseline: 2.3950x; 2.3950x over previous
//
#include <hip/hip_runtime.h>
#include <math.h>

// ---------------------------------------------------------------------------
// Phase 1: natural cubic spline coefficients, 3 channels. Single block.
// ---------------------------------------------------------------------------
__global__ void spline_setup(const float* __restrict__ delay_in,
                             const float* __restrict__ raw,
                             double* __restrict__ coef,
                             int* __restrict__ minz,
                             int nf) {
    extern __shared__ double smem[];
    double* xch = smem;           // 3*nf
    double* cp  = xch + 3 * nf;   // nf
    double* kk  = cp + nf;        // 3*nf

    int tid = threadIdx.x;
    if (tid == 0) *minz = 0x7fffffff;

    for (int i = tid; i < nf; i += blockDim.x) {
        double s0 = 1.0 / (1.0 + exp(-(double)raw[2 * i + 0]));
        double s1 = 1.0 / (1.0 + exp(-(double)raw[2 * i + 1]));
        double ss = s0 + s1;
        xch[0 * nf + i] = (double)delay_in[i];
        xch[1 * nf + i] = s0 / ss;
        xch[2 * nf + i] = s1 / ss;
    }
    __syncthreads();

    if (tid == 0) {
        cp[0] = 0.5;
        for (int i = 1; i < nf; ++i) {
            double d = (i == nf - 1) ? 2.0 : 4.0;
            cp[i] = 1.0 / (d - cp[i - 1]);
        }
    }
    __syncthreads();

    if (tid < 3) {
        const double* x = xch + tid * nf;
        double* k = kk + tid * nf;
        double hinv = (double)(nf - 1);
        double prev = 0.0;
        for (int j = 0; j < nf; ++j) {
            double r = 0.0;
            if (j < nf - 1) r += 3.0 * hinv * (x[j + 1] - x[j]);
            if (j > 0)      r += 3.0 * hinv * (x[j] - x[j - 1]);
            double dp = (r - prev) * cp[j];
            k[j] = dp;
            prev = dp;
        }
        for (int j = nf - 2; j >= 0; --j) k[j] = k[j] - cp[j] * k[j + 1];
    }
    __syncthreads();

    int nint = nf - 1;
    double hinv = (double)(nf - 1);
    for (int w = tid; w < 3 * nint; w += blockDim.x) {
        int ch = w / nint;
        int i = w - ch * nint;
        const double* x = xch + ch * nf;
        const double* k = kk + ch * nf;
        double dx3 = 3.0 * (x[i + 1] - x[i]);
        double two_c   = (2.0 * dx3 * hinv - 4.0 * k[i] - 2.0 * k[i + 1]) * hinv;
        double three_d = (-2.0 * dx3 * hinv + 3.0 * (k[i] + k[i + 1])) * hinv * hinv;
        double* C = coef + (size_t)(ch * nint + i) * 4;
        C[0] = x[i];
        C[1] = k[i];
        C[2] = 0.5 * two_c;
        C[3] = three_d * (1.0 / 3.0);
    }
}

// ---------------------------------------------------------------------------
// Phase 2: per-sample spline eval -> {g1, g2, g3, s3} one float4.
// s3 = (t - z - 3) & 1023 : base slot of the 3 contiguous history reads
// (slots s3, s3+1, s3+2; slots 1024/1025 shadow 0/1 in the scan buffer).
// Global min z via one atomic per wave. Pads [n, nTot) with zeros.
// ---------------------------------------------------------------------------
__global__ void eval_kernel(const double* __restrict__ coef,
                            float4* __restrict__ gx,
                            int* __restrict__ minz,
                            int n, int nTot, int nf) {
    int j = blockIdx.x * blockDim.x + threadIdx.x;
    if (j >= nTot) return;
    if (j >= n) { gx[j] = make_float4(0.f, 0.f, 0.f, 0.f); return; }

    double u = (double)j / (double)(n - 1);
    double nfm1 = (double)(nf - 1);
    int idx = (int)(u * nfm1);
    if (idx > nf - 2) idx = nf - 2;
    if (idx < 0) idx = 0;
    double tknot = (double)idx / nfm1;
    if (u < tknot && idx > 0) {
        idx--; tknot = (double)idx / nfm1;
    } else {
        double tnext = (double)(idx + 1) / nfm1;
        if (u >= tnext && idx < nf - 2) { idx++; tknot = tnext; }
    }
    double f = u - tknot;

    int nint = nf - 1;
    const double* C0 = coef + (size_t)(0 * nint + idx) * 4;
    const double* C1 = coef + (size_t)(1 * nint + idx) * 4;
    const double* C2 = coef + (size_t)(2 * nint + idx) * 4;
    double dly = C0[0] + f * (C0[1] + f * (C0[2] + f * C0[3]));
    double b1d = C1[0] + f * (C1[1] + f * (C1[2] + f * C1[3]));
    double b2d = C2[0] + f * (C2[1] + f * (C2[2] + f * C2[3]));

    double zf = floor(dly);
    int z = (int)zf;
    float alfa = (float)(dly - zf);
    float b1 = (float)b1d, b2 = (float)b2d;
    float g1 = b1 * (1.0f - alfa);
    float g2 = b1 * alfa + b2 * (1.0f - alfa);
    float g3 = b2 * alfa;

    int s3 = (j - z - 3) & 1023;
    gx[j] = make_float4(g1, g2, g3, __uint_as_float((unsigned int)s3));

    int wmin = z;
    #pragma unroll
    for (int o = 32; o > 0; o >>= 1) wmin = min(wmin, __shfl_down(wmin, o, 64));
    if ((threadIdx.x & 63) == 0) atomicMin(minz, wmin);
}

// ---------------------------------------------------------------------------
// Phase 3: wave-synchronous fixed-chunk recurrence. ONE wave, no barriers.
// D = min(z)+1 clamped to [4,128]; chunk = 2 rows of 64 lanes.
// Invariants: every history read of a chunk targets positions < base
// (D <= minz+1), and z+3 <= 1023, so source-order "all reads, then all
// writes" is both correct and the only ordering the compiler must keep.
// Single-wave in-order LDS pipe orders chunk i writes before chunk i+1 reads.
// gx stream prefetched 4 chunks deep via an unroll-by-4 register pipeline
// with pure-arithmetic addresses (no table, no rotation movs).
// ---------------------------------------------------------------------------
__global__ void __launch_bounds__(64) scan_kernel(const float4* __restrict__ gx,
                                                  const int* __restrict__ minz,
                                                  const float* __restrict__ exc,
                                                  float* __restrict__ y,
                                                  int n, int burst) {
    __shared__ float buf[1026];   // 1024 circular + 2 shadow (mirror slots 0,1)
    __shared__ float excl[2048];

    int tid = threadIdx.x;
    for (int i = tid; i < 1026; i += 64) buf[i] = 0.0f;
    for (int i = tid; i < 2048; i += 64) excl[i] = (i < burst) ? exc[i] : 0.0f;
    // single wave: in-order LDS pipe, no barrier needed.

    int D = __builtin_amdgcn_readfirstlane(*minz) + 1;
    if (D > 128) D = 128;
    if (D < 4) D = 4;
    int nIter = (n + D - 1) / D;

#define LDP(pa, pb, c)                    \
    {                                     \
        int _b = (c) * D;                 \
        pa = gx[_b + tid];                \
        pb = gx[_b + 64 + tid];           \
    }

#define BODY(pa, pb, c)                                                       \
    {                                                                         \
        int base = (c) * D;                                                   \
        int t0 = base + tid;                                                  \
        int t1 = t0 + 64;                                                     \
        unsigned int s0 = __float_as_uint((pa).w);                            \
        unsigned int s1 = __float_as_uint((pb).w);                            \
        /* all reads before any write (source order = required order) */      \
        float a3 = buf[s0];                                                   \
        float a2 = buf[s0 + 1];                                               \
        float a1 = buf[s0 + 2];                                               \
        float b3 = buf[s1];                                                   \
        float b2 = buf[s1 + 1];                                               \
        float b1 = buf[s1 + 2];                                               \
        float xa = 0.0f, xb = 0.0f;                                           \
        if (base < burst) { /* scalar-uniform; taken only first ~20 chunks */ \
            float ra = excl[t0 & 2047];                                       \
            float rb = excl[t1 & 2047];                                       \
            xa = (t0 < burst) ? ra : 0.0f;                                    \
            xb = (t1 < burst) ? rb : 0.0f;                                    \
        }                                                                     \
        float ya = fmaf((pa).x, a1, xa);                                      \
        ya = fmaf((pa).y, a2, ya);                                            \
        ya = fmaf((pa).z, a3, ya);                                            \
        float yb = fmaf((pb).x, b1, xb);                                      \
        yb = fmaf((pb).y, b2, yb);                                            \
        yb = fmaf((pb).z, b3, yb);                                            \
        if ((tid < D) && (t0 < n)) {                                          \
            int w = t0 & 1023;                                                \
            buf[w] = ya;                                                      \
            if (w < 2) buf[1024 + w] = ya;                                    \
            y[t0] = ya;                                                       \
        }                                                                     \
        if ((64 + tid < D) && (t1 < n)) {                                     \
            int w = t1 & 1023;                                                \
            buf[w] = yb;                                                      \
            if (w < 2) buf[1024 + w] = yb;                                    \
            y[t1] = yb;                                                       \
        }                                                                     \
    }

    float4 p0a, p0b, p1a, p1b, p2a, p2b, p3a, p3b;
    LDP(p0a, p0b, 0)
    LDP(p1a, p1b, 1)
    LDP(p2a, p2b, 2)
    LDP(p3a, p3b, 3)

    int nG = (nIter + 3) / 4;
    for (int g = 0; g < nG; ++g) {
        int c0 = 4 * g;
        BODY(p0a, p0b, c0 + 0) LDP(p0a, p0b, c0 + 4)
        BODY(p1a, p1b, c0 + 1) LDP(p1a, p1b, c0 + 5)
        BODY(p2a, p2b, c0 + 2) LDP(p2a, p2b, c0 + 6)
        BODY(p3a, p3b, c0 + 3) LDP(p3a, p3b, c0 + 7)
    }
#undef BODY
#undef LDP
}

// ---------------------------------------------------------------------------
extern "C" void kernel_launch(void* const* d_in, const int* in_sizes, int n_in,
                              void* d_out, int out_size, void* d_ws, size_t ws_size,
                              hipStream_t stream) {
    const float* delay = (const float*)d_in[0];
    const float* raw   = (const float*)d_in[1];
    const float* exc   = (const float*)d_in[2];
    int nf = in_sizes[0];
    int burst = in_sizes[2];
    if (burst > 2048) burst = 2048;
    int n = out_size;
    int nTot = n + 1024;   // pad covers prefetch overshoot: 4 chunks * 128 + 128

    char* ws = (char*)d_ws;
    size_t coefBytes = (size_t)3 * (nf - 1) * 4 * sizeof(double);
    size_t off = (coefBytes + 255) & ~(size_t)255;
    double* coef = (double*)ws;
    int* minz = (int*)(ws + off);
    off += 256;
    float4* gxa = (float4*)(ws + off);

    size_t shmem = (size_t)(7 * nf) * sizeof(double);
    spline_setup<<<1, 64, shmem, stream>>>(delay, raw, coef, minz, nf);
    eval_kernel<<<(nTot + 255) / 256, 256, 0, stream>>>(coef, gxa, minz, n, nTot, nf);
    scan_kernel<<<1, 64, 0, stream>>>(gxa, minz, exc, (float*)d_out, n, burst);
}

// Round 6
// 393.257 us; speedup vs baseline: 2.4604x; 1.0273x over previous
//
#include <hip/hip_runtime.h>
#include <math.h>

// ---------------------------------------------------------------------------
// Phase 1: natural cubic spline coefficients, 3 channels. Single block.
// ---------------------------------------------------------------------------
__global__ void spline_setup(const float* __restrict__ delay_in,
                             const float* __restrict__ raw,
                             double* __restrict__ coef,
                             int* __restrict__ minz,
                             int nf) {
    extern __shared__ double smem[];
    double* xch = smem;           // 3*nf
    double* cp  = xch + 3 * nf;   // nf
    double* kk  = cp + nf;        // 3*nf

    int tid = threadIdx.x;
    if (tid == 0) *minz = 0x7fffffff;

    for (int i = tid; i < nf; i += blockDim.x) {
        double s0 = 1.0 / (1.0 + exp(-(double)raw[2 * i + 0]));
        double s1 = 1.0 / (1.0 + exp(-(double)raw[2 * i + 1]));
        double ss = s0 + s1;
        xch[0 * nf + i] = (double)delay_in[i];
        xch[1 * nf + i] = s0 / ss;
        xch[2 * nf + i] = s1 / ss;
    }
    __syncthreads();

    if (tid == 0) {
        cp[0] = 0.5;
        for (int i = 1; i < nf; ++i) {
            double d = (i == nf - 1) ? 2.0 : 4.0;
            cp[i] = 1.0 / (d - cp[i - 1]);
        }
    }
    __syncthreads();

    if (tid < 3) {
        const double* x = xch + tid * nf;
        double* k = kk + tid * nf;
        double hinv = (double)(nf - 1);
        double prev = 0.0;
        for (int j = 0; j < nf; ++j) {
            double r = 0.0;
            if (j < nf - 1) r += 3.0 * hinv * (x[j + 1] - x[j]);
            if (j > 0)      r += 3.0 * hinv * (x[j] - x[j - 1]);
            double dp = (r - prev) * cp[j];
            k[j] = dp;
            prev = dp;
        }
        for (int j = nf - 2; j >= 0; --j) k[j] = k[j] - cp[j] * k[j + 1];
    }
    __syncthreads();

    int nint = nf - 1;
    double hinv = (double)(nf - 1);
    for (int w = tid; w < 3 * nint; w += blockDim.x) {
        int ch = w / nint;
        int i = w - ch * nint;
        const double* x = xch + ch * nf;
        const double* k = kk + ch * nf;
        double dx3 = 3.0 * (x[i + 1] - x[i]);
        double two_c   = (2.0 * dx3 * hinv - 4.0 * k[i] - 2.0 * k[i + 1]) * hinv;
        double three_d = (-2.0 * dx3 * hinv + 3.0 * (k[i] + k[i + 1])) * hinv * hinv;
        double* C = coef + (size_t)(ch * nint + i) * 4;
        C[0] = x[i];
        C[1] = k[i];
        C[2] = 0.5 * two_c;
        C[3] = three_d * (1.0 / 3.0);
    }
}

// ---------------------------------------------------------------------------
// Phase 2: per-sample spline eval -> {g1, g2, g3, pk} one float4.
// pk packs the 3 wrapped history slots: r_i = (t - z - i) & 1023,
// pk = (r1<<20)|(r2<<10)|r3. Global min z via one atomic per wave.
// Pads [n, nTot) with zeros so the scan's deep prefetch loads unguarded.
// ---------------------------------------------------------------------------
__global__ void eval_kernel(const double* __restrict__ coef,
                            float4* __restrict__ gx,
                            int* __restrict__ minz,
                            int n, int nTot, int nf) {
    int j = blockIdx.x * blockDim.x + threadIdx.x;
    if (j >= nTot) return;
    if (j >= n) { gx[j] = make_float4(0.f, 0.f, 0.f, 0.f); return; }

    double u = (double)j / (double)(n - 1);
    double nfm1 = (double)(nf - 1);
    int idx = (int)(u * nfm1);
    if (idx > nf - 2) idx = nf - 2;
    if (idx < 0) idx = 0;
    double tknot = (double)idx / nfm1;
    if (u < tknot && idx > 0) {
        idx--; tknot = (double)idx / nfm1;
    } else {
        double tnext = (double)(idx + 1) / nfm1;
        if (u >= tnext && idx < nf - 2) { idx++; tknot = tnext; }
    }
    double f = u - tknot;

    int nint = nf - 1;
    const double* C0 = coef + (size_t)(0 * nint + idx) * 4;
    const double* C1 = coef + (size_t)(1 * nint + idx) * 4;
    const double* C2 = coef + (size_t)(2 * nint + idx) * 4;
    double dly = C0[0] + f * (C0[1] + f * (C0[2] + f * C0[3]));
    double b1d = C1[0] + f * (C1[1] + f * (C1[2] + f * C1[3]));
    double b2d = C2[0] + f * (C2[1] + f * (C2[2] + f * C2[3]));

    double zf = floor(dly);
    int z = (int)zf;
    float alfa = (float)(dly - zf);
    float b1 = (float)b1d, b2 = (float)b2d;
    float g1 = b1 * (1.0f - alfa);
    float g2 = b1 * alfa + b2 * (1.0f - alfa);
    float g3 = b2 * alfa;

    int r1 = (j - z - 1) & 1023;
    int r2 = (j - z - 2) & 1023;
    int r3 = (j - z - 3) & 1023;
    unsigned int pk = (unsigned int)((r1 << 20) | (r2 << 10) | r3);
    gx[j] = make_float4(g1, g2, g3, __uint_as_float(pk));

    int wmin = z;
    #pragma unroll
    for (int o = 32; o > 0; o >>= 1) wmin = min(wmin, __shfl_down(wmin, o, 64));
    if ((threadIdx.x & 63) == 0) atomicMin(minz, wmin);
}

// ---------------------------------------------------------------------------
// Phase 3: wave-synchronous fixed-chunk recurrence. ONE wave, no barriers.
// D = min(z)+1 clamped to [4,128]; chunk = 2 rows of 64 lanes.
// Invariants: every history read of a chunk targets positions < base
// (D <= minz+1), so per-body "all reads, then all writes" is correct; the
// single-wave in-order LDS pipe orders chunk i writes before chunk i+1 reads.
// gx stream prefetched EIGHT chunks deep (16 float4 in flight) via an
// unroll-by-8 register pipeline with pure-arithmetic addresses — covers
// ~900-1200 cy of cross-XCD / HBM load latency at the ~150 cy/chunk LDS
// floor (round-5 post-mortem: distance-4 exposed ~450 cy/chunk).
// ---------------------------------------------------------------------------
__global__ void __launch_bounds__(64) scan_kernel(const float4* __restrict__ gx,
                                                  const int* __restrict__ minz,
                                                  const float* __restrict__ exc,
                                                  float* __restrict__ y,
                                                  int n, int burst) {
    __shared__ float buf[1024];
    __shared__ float excl[2048];

    int tid = threadIdx.x;
    for (int i = tid; i < 1024; i += 64) buf[i] = 0.0f;
    for (int i = tid; i < 2048; i += 64) excl[i] = (i < burst) ? exc[i] : 0.0f;
    // single wave: in-order LDS pipe, no barrier needed.

    int D = __builtin_amdgcn_readfirstlane(*minz) + 1;
    if (D > 128) D = 128;
    if (D < 4) D = 4;
    int nIter = (n + D - 1) / D;

#define LDP(pa, pb, c)                    \
    {                                     \
        int _b = (c) * D;                 \
        pa = gx[_b + tid];                \
        pb = gx[_b + 64 + tid];           \
    }

#define BODY(pa, pb, c)                                                       \
    {                                                                         \
        int base = (c) * D;                                                   \
        int t0 = base + tid;                                                  \
        int t1 = t0 + 64;                                                     \
        unsigned int k0 = __float_as_uint((pa).w);                            \
        unsigned int k1 = __float_as_uint((pb).w);                            \
        /* all reads before any write (source order = required order) */      \
        float a1 = buf[k0 >> 20];                                             \
        float a2 = buf[(k0 >> 10) & 1023];                                    \
        float a3 = buf[k0 & 1023];                                            \
        float b1 = buf[k1 >> 20];                                             \
        float b2 = buf[(k1 >> 10) & 1023];                                    \
        float b3 = buf[k1 & 1023];                                            \
        float xa = 0.0f, xb = 0.0f;                                           \
        if (base < burst) { /* chunk-uniform; taken only first ~20 chunks */  \
            float ra = excl[t0 & 2047];                                       \
            float rb = excl[t1 & 2047];                                       \
            xa = (t0 < burst) ? ra : 0.0f;                                    \
            xb = (t1 < burst) ? rb : 0.0f;                                    \
        }                                                                     \
        float ya = fmaf((pa).x, a1, xa);                                      \
        ya = fmaf((pa).y, a2, ya);                                            \
        ya = fmaf((pa).z, a3, ya);                                            \
        float yb = fmaf((pb).x, b1, xb);                                      \
        yb = fmaf((pb).y, b2, yb);                                            \
        yb = fmaf((pb).z, b3, yb);                                            \
        if ((tid < D) && (t0 < n)) {                                          \
            buf[t0 & 1023] = ya;                                              \
            y[t0] = ya;                                                       \
        }                                                                     \
        if ((64 + tid < D) && (t1 < n)) {                                     \
            buf[t1 & 1023] = yb;                                              \
            y[t1] = yb;                                                       \
        }                                                                     \
    }

    float4 p0a, p0b, p1a, p1b, p2a, p2b, p3a, p3b;
    float4 p4a, p4b, p5a, p5b, p6a, p6b, p7a, p7b;
    LDP(p0a, p0b, 0)
    LDP(p1a, p1b, 1)
    LDP(p2a, p2b, 2)
    LDP(p3a, p3b, 3)
    LDP(p4a, p4b, 4)
    LDP(p5a, p5b, 5)
    LDP(p6a, p6b, 6)
    LDP(p7a, p7b, 7)

    int nG = (nIter + 7) / 8;
    for (int g = 0; g < nG; ++g) {
        int c0 = 8 * g;
        BODY(p0a, p0b, c0 + 0) LDP(p0a, p0b, c0 + 8)
        BODY(p1a, p1b, c0 + 1) LDP(p1a, p1b, c0 + 9)
        BODY(p2a, p2b, c0 + 2) LDP(p2a, p2b, c0 + 10)
        BODY(p3a, p3b, c0 + 3) LDP(p3a, p3b, c0 + 11)
        BODY(p4a, p4b, c0 + 4) LDP(p4a, p4b, c0 + 12)
        BODY(p5a, p5b, c0 + 5) LDP(p5a, p5b, c0 + 13)
        BODY(p6a, p6b, c0 + 6) LDP(p6a, p6b, c0 + 14)
        BODY(p7a, p7b, c0 + 7) LDP(p7a, p7b, c0 + 15)
    }
#undef BODY
#undef LDP
}

// ---------------------------------------------------------------------------
extern "C" void kernel_launch(void* const* d_in, const int* in_sizes, int n_in,
                              void* d_out, int out_size, void* d_ws, size_t ws_size,
                              hipStream_t stream) {
    const float* delay = (const float*)d_in[0];
    const float* raw   = (const float*)d_in[1];
    const float* exc   = (const float*)d_in[2];
    int nf = in_sizes[0];
    int burst = in_sizes[2];
    if (burst > 2048) burst = 2048;
    int n = out_size;
    int nTot = n + 4096;   // pad covers distance-8 prefetch overshoot (<= 16*128 + 128)

    char* ws = (char*)d_ws;
    size_t coefBytes = (size_t)3 * (nf - 1) * 4 * sizeof(double);
    size_t off = (coefBytes + 255) & ~(size_t)255;
    double* coef = (double*)ws;
    int* minz = (int*)(ws + off);
    off += 256;
    float4* gxa = (float4*)(ws + off);

    size_t shmem = (size_t)(7 * nf) * sizeof(double);
    spline_setup<<<1, 64, shmem, stream>>>(delay, raw, coef, minz, nf);
    eval_kernel<<<(nTot + 255) / 256, 256, 0, stream>>>(coef, gxa, minz, n, nTot, nf);
    scan_kernel<<<1, 64, 0, stream>>>(gxa, minz, exc, (float*)d_out, n, burst);
}

// Round 7
// 393.000 us; speedup vs baseline: 2.4620x; 1.0007x over previous
//
#include <hip/hip_runtime.h>
#include <math.h>

// ---------------------------------------------------------------------------
// Phase 1: natural cubic spline coefficients, 3 channels. Single block.
// ---------------------------------------------------------------------------
__global__ void spline_setup(const float* __restrict__ delay_in,
                             const float* __restrict__ raw,
                             double* __restrict__ coef,
                             int* __restrict__ minz,
                             int nf) {
    extern __shared__ double smem[];
    double* xch = smem;           // 3*nf
    double* cp  = xch + 3 * nf;   // nf
    double* kk  = cp + nf;        // 3*nf

    int tid = threadIdx.x;
    if (tid == 0) *minz = 0x7fffffff;

    for (int i = tid; i < nf; i += blockDim.x) {
        double s0 = 1.0 / (1.0 + exp(-(double)raw[2 * i + 0]));
        double s1 = 1.0 / (1.0 + exp(-(double)raw[2 * i + 1]));
        double ss = s0 + s1;
        xch[0 * nf + i] = (double)delay_in[i];
        xch[1 * nf + i] = s0 / ss;
        xch[2 * nf + i] = s1 / ss;
    }
    __syncthreads();

    if (tid == 0) {
        cp[0] = 0.5;
        for (int i = 1; i < nf; ++i) {
            double d = (i == nf - 1) ? 2.0 : 4.0;
            cp[i] = 1.0 / (d - cp[i - 1]);
        }
    }
    __syncthreads();

    if (tid < 3) {
        const double* x = xch + tid * nf;
        double* k = kk + tid * nf;
        double hinv = (double)(nf - 1);
        double prev = 0.0;
        for (int j = 0; j < nf; ++j) {
            double r = 0.0;
            if (j < nf - 1) r += 3.0 * hinv * (x[j + 1] - x[j]);
            if (j > 0)      r += 3.0 * hinv * (x[j] - x[j - 1]);
            double dp = (r - prev) * cp[j];
            k[j] = dp;
            prev = dp;
        }
        for (int j = nf - 2; j >= 0; --j) k[j] = k[j] - cp[j] * k[j + 1];
    }
    __syncthreads();

    int nint = nf - 1;
    double hinv = (double)(nf - 1);
    for (int w = tid; w < 3 * nint; w += blockDim.x) {
        int ch = w / nint;
        int i = w - ch * nint;
        const double* x = xch + ch * nf;
        const double* k = kk + ch * nf;
        double dx3 = 3.0 * (x[i + 1] - x[i]);
        double two_c   = (2.0 * dx3 * hinv - 4.0 * k[i] - 2.0 * k[i + 1]) * hinv;
        double three_d = (-2.0 * dx3 * hinv + 3.0 * (k[i] + k[i + 1])) * hinv * hinv;
        double* C = coef + (size_t)(ch * nint + i) * 4;
        C[0] = x[i];
        C[1] = k[i];
        C[2] = 0.5 * two_c;
        C[3] = three_d * (1.0 / 3.0);
    }
}

// ---------------------------------------------------------------------------
// Phase 2: per-sample spline eval -> {g1, g2, g3, pk} one float4.
// pk packs the 3 wrapped history slots: r_i = (t - z - i) & 1023,
// pk = (r1<<20)|(r2<<10)|r3. Global min z via one atomic per wave.
// Pads [n, nTot) with zeros so the scan's deep prefetch loads unguarded.
// ---------------------------------------------------------------------------
__global__ void eval_kernel(const double* __restrict__ coef,
                            float4* __restrict__ gx,
                            int* __restrict__ minz,
                            int n, int nTot, int nf) {
    int j = blockIdx.x * blockDim.x + threadIdx.x;
    if (j >= nTot) return;
    if (j >= n) { gx[j] = make_float4(0.f, 0.f, 0.f, 0.f); return; }

    double u = (double)j / (double)(n - 1);
    double nfm1 = (double)(nf - 1);
    int idx = (int)(u * nfm1);
    if (idx > nf - 2) idx = nf - 2;
    if (idx < 0) idx = 0;
    double tknot = (double)idx / nfm1;
    if (u < tknot && idx > 0) {
        idx--; tknot = (double)idx / nfm1;
    } else {
        double tnext = (double)(idx + 1) / nfm1;
        if (u >= tnext && idx < nf - 2) { idx++; tknot = tnext; }
    }
    double f = u - tknot;

    int nint = nf - 1;
    const double* C0 = coef + (size_t)(0 * nint + idx) * 4;
    const double* C1 = coef + (size_t)(1 * nint + idx) * 4;
    const double* C2 = coef + (size_t)(2 * nint + idx) * 4;
    double dly = C0[0] + f * (C0[1] + f * (C0[2] + f * C0[3]));
    double b1d = C1[0] + f * (C1[1] + f * (C1[2] + f * C1[3]));
    double b2d = C2[0] + f * (C2[1] + f * (C2[2] + f * C2[3]));

    double zf = floor(dly);
    int z = (int)zf;
    float alfa = (float)(dly - zf);
    float b1 = (float)b1d, b2 = (float)b2d;
    float g1 = b1 * (1.0f - alfa);
    float g2 = b1 * alfa + b2 * (1.0f - alfa);
    float g3 = b2 * alfa;

    int r1 = (j - z - 1) & 1023;
    int r2 = (j - z - 2) & 1023;
    int r3 = (j - z - 3) & 1023;
    unsigned int pk = (unsigned int)((r1 << 20) | (r2 << 10) | r3);
    gx[j] = make_float4(g1, g2, g3, __uint_as_float(pk));

    int wmin = z;
    #pragma unroll
    for (int o = 32; o > 0; o >>= 1) wmin = min(wmin, __shfl_down(wmin, o, 64));
    if ((threadIdx.x & 63) == 0) atomicMin(minz, wmin);
}

// ---------------------------------------------------------------------------
// Phase 3: wave-synchronous fixed-chunk recurrence. ONE wave, no barriers.
// D = min(z)+1 clamped to [4,128]; chunk = 2 rows of 64 lanes.
// Invariants: every history read of a chunk targets positions < base
// (D <= minz+1), so per-body "all reads, then all writes" is correct; the
// single-wave in-order LDS pipe orders chunk i writes before chunk i+1 reads.
// gx stream prefetched EIGHT chunks deep (16 float4 = 64 VGPR in flight).
// __launch_bounds__(64, 1) + amdgpu_waves_per_eu(1,1): exactly ONE wave runs;
// tell the register allocator so it doesn't budget for 8-wave occupancy and
// sink the prefetch loads (round-6 post-mortem: VGPR_Count=56 proved the
// 64-VGPR pipeline was never materialized and loads ran at distance ~0).
// ---------------------------------------------------------------------------
__global__ void __launch_bounds__(64, 1)
__attribute__((amdgpu_waves_per_eu(1, 1)))
scan_kernel(const float4* __restrict__ gx,
            const int* __restrict__ minz,
            const float* __restrict__ exc,
            float* __restrict__ y,
            int n, int burst) {
    __shared__ float buf[1024];
    __shared__ float excl[2048];

    int tid = threadIdx.x;
    for (int i = tid; i < 1024; i += 64) buf[i] = 0.0f;
    for (int i = tid; i < 2048; i += 64) excl[i] = (i < burst) ? exc[i] : 0.0f;
    // single wave: in-order LDS pipe, no barrier needed.

    int D = __builtin_amdgcn_readfirstlane(*minz) + 1;
    if (D > 128) D = 128;
    if (D < 4) D = 4;
    int nIter = (n + D - 1) / D;

#define LDP(pa, pb, c)                    \
    {                                     \
        int _b = (c) * D;                 \
        pa = gx[_b + tid];                \
        pb = gx[_b + 64 + tid];           \
    }

#define BODY(pa, pb, c)                                                       \
    {                                                                         \
        int base = (c) * D;                                                   \
        int t0 = base + tid;                                                  \
        int t1 = t0 + 64;                                                     \
        unsigned int k0 = __float_as_uint((pa).w);                            \
        unsigned int k1 = __float_as_uint((pb).w);                            \
        /* all reads before any write (source order = required order) */      \
        float a1 = buf[k0 >> 20];                                             \
        float a2 = buf[(k0 >> 10) & 1023];                                    \
        float a3 = buf[k0 & 1023];                                            \
        float b1 = buf[k1 >> 20];                                             \
        float b2 = buf[(k1 >> 10) & 1023];                                    \
        float b3 = buf[k1 & 1023];                                            \
        float xa = 0.0f, xb = 0.0f;                                           \
        if (base < burst) { /* chunk-uniform; taken only first ~20 chunks */  \
            float ra = excl[t0 & 2047];                                       \
            float rb = excl[t1 & 2047];                                       \
            xa = (t0 < burst) ? ra : 0.0f;                                    \
            xb = (t1 < burst) ? rb : 0.0f;                                    \
        }                                                                     \
        float ya = fmaf((pa).x, a1, xa);                                      \
        ya = fmaf((pa).y, a2, ya);                                            \
        ya = fmaf((pa).z, a3, ya);                                            \
        float yb = fmaf((pb).x, b1, xb);                                      \
        yb = fmaf((pb).y, b2, yb);                                            \
        yb = fmaf((pb).z, b3, yb);                                            \
        if ((tid < D) && (t0 < n)) {                                          \
            buf[t0 & 1023] = ya;                                              \
            y[t0] = ya;                                                       \
        }                                                                     \
        if ((64 + tid < D) && (t1 < n)) {                                     \
            buf[t1 & 1023] = yb;                                              \
            y[t1] = yb;                                                       \
        }                                                                     \
    }

    float4 p0a, p0b, p1a, p1b, p2a, p2b, p3a, p3b;
    float4 p4a, p4b, p5a, p5b, p6a, p6b, p7a, p7b;
    LDP(p0a, p0b, 0)
    LDP(p1a, p1b, 1)
    LDP(p2a, p2b, 2)
    LDP(p3a, p3b, 3)
    LDP(p4a, p4b, 4)
    LDP(p5a, p5b, 5)
    LDP(p6a, p6b, 6)
    LDP(p7a, p7b, 7)

    int nG = (nIter + 7) / 8;
    for (int g = 0; g < nG; ++g) {
        int c0 = 8 * g;
        BODY(p0a, p0b, c0 + 0) LDP(p0a, p0b, c0 + 8)
        BODY(p1a, p1b, c0 + 1) LDP(p1a, p1b, c0 + 9)
        BODY(p2a, p2b, c0 + 2) LDP(p2a, p2b, c0 + 10)
        BODY(p3a, p3b, c0 + 3) LDP(p3a, p3b, c0 + 11)
        BODY(p4a, p4b, c0 + 4) LDP(p4a, p4b, c0 + 12)
        BODY(p5a, p5b, c0 + 5) LDP(p5a, p5b, c0 + 13)
        BODY(p6a, p6b, c0 + 6) LDP(p6a, p6b, c0 + 14)
        BODY(p7a, p7b, c0 + 7) LDP(p7a, p7b, c0 + 15)
    }
#undef BODY
#undef LDP
}

// ---------------------------------------------------------------------------
extern "C" void kernel_launch(void* const* d_in, const int* in_sizes, int n_in,
                              void* d_out, int out_size, void* d_ws, size_t ws_size,
                              hipStream_t stream) {
    const float* delay = (const float*)d_in[0];
    const float* raw   = (const float*)d_in[1];
    const float* exc   = (const float*)d_in[2];
    int nf = in_sizes[0];
    int burst = in_sizes[2];
    if (burst > 2048) burst = 2048;
    int n = out_size;
    int nTot = n + 4096;   // pad covers distance-8 prefetch overshoot (<= 16*128 + 128)

    char* ws = (char*)d_ws;
    size_t coefBytes = (size_t)3 * (nf - 1) * 4 * sizeof(double);
    size_t off = (coefBytes + 255) & ~(size_t)255;
    double* coef = (double*)ws;
    int* minz = (int*)(ws + off);
    off += 256;
    float4* gxa = (float4*)(ws + off);

    size_t shmem = (size_t)(7 * nf) * sizeof(double);
    spline_setup<<<1, 64, shmem, stream>>>(delay, raw, coef, minz, nf);
    eval_kernel<<<(nTot + 255) / 256, 256, 0, stream>>>(coef, gxa, minz, n, nTot, nf);
    scan_kernel<<<1, 64, 0, stream>>>(gxa, minz, exc, (float*)d_out, n, burst);
}